// Round 9
// baseline (268.432 us; speedup 1.0000x reference)
//
#include <hip/hip_runtime.h>

typedef _Float16 h16;
typedef _Float16 half8 __attribute__((ext_vector_type(8)));
typedef float floatx4 __attribute__((ext_vector_type(4)));

static constexpr int Bb_ = 4, S_ = 2048, D_ = 1024;

static __device__ __forceinline__ void gl_lds16(const void* g, void* l) {
  __builtin_amdgcn_global_load_lds(
      (const __attribute__((address_space(1))) unsigned int*)g,
      (__attribute__((address_space(3))) unsigned int*)l, 16, 0, 0);
}

// one 2x2 Givens pair: y = (Rq^T Rk) q (combined, normalized), v = Rv q
static __device__ __forceinline__ void rot_pair(float q0, float q1, float a0,
                                                float a1, float b0, float b1,
                                                float c0, float c1, float& y0,
                                                float& y1, float& v0,
                                                float& v1) {
  float iqk = rsqrtf((a0 * a0 + a1 * a1) * (b0 * b0 + b1 * b1));
  float cc = (a0 * b0 + a1 * b1) * iqk;
  float ss = (a0 * b1 - a1 * b0) * iqk;
  y0 = cc * q0 - ss * q1;
  y1 = cc * q1 + ss * q0;
  float iv = rsqrtf(c0 * c0 + c1 * c1);
  float cv = c0 * iv, sv = c1 * iv;
  v0 = cv * q0 - sv * q1;
  v1 = cv * q1 + sv * q0;
}

// ---------------- R9 MEGA-KERNEL ----------------
// Ledger across R4-R7 shows a stable ~56 us of inter-dispatch overhead
// (total - sum(kernels)), ~15-19 us per launch boundary. This round merges
// prep + GEMM1 + GEMM2(+normalize) into ONE kernel: grid 256 x 512thr x
// 128KiB LDS = exactly 1 block/CU, all co-resident (the residency guarantee
// GEMM2's group-sync already validated on HW). Stages separated by a
// device-wide ticket barrier: add to a monotone counter, spin until
// >= (ticket/256+1)*256 (wrap-safe; counter zeroed per-launch by an in-graph
// hipMemsetAsync, so rocprof replays are safe). __threadfence() + acq_rel
// atomics provide the cross-XCD L2 writeback/invalidate needed for the
// plain-store -> barrier -> global_load_lds handoff between stages.
// K-loop: reverted to the R4 form (best measured: 43.9/43.9 us, vs R8's
// m201-exact port which regressed to 57.2 -> theory falsified).
// GEMM1 epilogue: P = exp(l*alpha - 8) (constant shift cancels under the
// final normalize; alpha*l ~ N(0,4) cannot overflow fp16).
// GEMM2 epilogue: fused row-normalize via agent-scope atomicAdd pss +
// XCD-local groups + flag spin (unchanged from R7, HW-validated).

#define G_FENCE asm volatile("" ::: "memory")
#define G_BAR                     \
  do {                            \
    G_FENCE;                      \
    __builtin_amdgcn_s_barrier(); \
    G_FENCE;                      \
  } while (0)

// device-wide ticket barrier (uniform call site only)
static __device__ __forceinline__ void dev_barrier(unsigned int* bar, int t) {
  __syncthreads();
  if (t == 0) {
    __threadfence();  // release: write back this XCD's dirty L2 lines
    unsigned int ticket = __hip_atomic_fetch_add(bar, 1u, __ATOMIC_ACQ_REL,
                                                 __HIP_MEMORY_SCOPE_AGENT);
    unsigned int target = (ticket / 256u + 1u) * 256u;
    while ((int)(__hip_atomic_load(bar, __ATOMIC_ACQUIRE,
                                   __HIP_MEMORY_SCOPE_AGENT) -
                 target) < 0)
      __builtin_amdgcn_s_sleep(2);
    __threadfence();  // acquire: invalidate stale lines before stage reads
  }
  __syncthreads();
}

#define AS_(bf, h) (as_base + ((bf)*2 + (h)) * 8192)
#define BS_(bf, h) (bs_base + ((bf)*2 + (h)) * 8192)

#define SG_A(bf, kt, hm)                                                  \
  do {                                                                    \
    const char* sp_ = Ab +                                                \
                      (unsigned long long)(srow + (hm) * 128) * a_pitch + \
                      (kt) * 128 + scol;                                  \
    gl_lds16(sp_, (char*)(AS_(bf, 0) + (hm)*128 * 32) + lds_o);           \
    gl_lds16(sp_ + 64, (char*)(AS_(bf, 1) + (hm)*128 * 32) + lds_o);      \
  } while (0)
#define SG_B(bf, kt, hm)                                                  \
  do {                                                                    \
    const char* sp_ = Bb +                                                \
                      (unsigned long long)(srow + (hm) * 128) * b_pitch + \
                      (kt) * 128 + scol;                                  \
    gl_lds16(sp_, (char*)(BS_(bf, 0) + (hm)*128 * 32) + lds_o);           \
    gl_lds16(sp_ + 64, (char*)(BS_(bf, 1) + (hm)*128 * 32) + lds_o);      \
  } while (0)
#define LDA_(bf, mh, DST)                                                   \
  do {                                                                     \
    _Pragma("unroll") for (int i_ = 0; i_ < 4; ++i_) {                     \
      DST[i_][0] = *(const half8*)&AS_(                                    \
          bf, 0)[(wm + ((mh)*4 + i_) * 16 + mrow) * 32 + koff];            \
      DST[i_][1] = *(const half8*)&AS_(                                    \
          bf, 1)[(wm + ((mh)*4 + i_) * 16 + mrow) * 32 + koff];            \
    }                                                                      \
  } while (0)
#define LDB_(bf, nh, DST)                                                   \
  do {                                                                     \
    _Pragma("unroll") for (int j_ = 0; j_ < JQ; ++j_) {                    \
      DST[j_][0] = *(const half8*)&BS_(                                    \
          bf, 0)[(wn + ((nh)*JQ + j_) * 16 + mrow) * 32 + koff];           \
      DST[j_][1] = *(const half8*)&BS_(                                    \
          bf, 1)[(wn + ((nh)*JQ + j_) * 16 + mrow) * 32 + koff];           \
    }                                                                      \
  } while (0)
#define QUAD(mh, nh, AF, BF)                                                \
  do {                                                                      \
    __builtin_amdgcn_s_setprio(1);                                          \
    _Pragma("unroll") for (int i_ = 0; i_ < 4; ++i_)                        \
        _Pragma("unroll") for (int j_ = 0; j_ < JQ; ++j_) {                 \
      acc[(mh)*4 + i_][(nh)*JQ + j_] =                                      \
          __builtin_amdgcn_mfma_f32_16x16x32_f16(                           \
              AF[i_][0], BF[j_][0], acc[(mh)*4 + i_][(nh)*JQ + j_], 0, 0,   \
              0);                                                           \
      acc[(mh)*4 + i_][(nh)*JQ + j_] =                                      \
          __builtin_amdgcn_mfma_f32_16x16x32_f16(                           \
              AF[i_][1], BF[j_][1], acc[(mh)*4 + i_][(nh)*JQ + j_], 0, 0,   \
              0);                                                           \
    }                                                                       \
    __builtin_amdgcn_s_setprio(0);                                          \
  } while (0)

// R4-form K-loop (best measured). Per phase: {stage; [vmcnt]; BAR;
// reads(next quad); MFMA(cur quad)}. Counted vmcnt only (never 0 in loop):
// prologue vmcnt drains exactly tile0; P3's vmcnt(6/4) drains exactly the
// next tile's half-slabs. Region-recycled LDS (B dead after P1, A after P2).
template <int NF, bool OUT16>
static __device__ __forceinline__ void gemm_body(
    int blk, int t, h16* as_base, h16* bs_base, const char* __restrict__ A,
    int a_pitch, unsigned long long a_batch, const char* __restrict__ Bt,
    int b_pitch, unsigned long long b_batch, void* __restrict__ C, int c_pitch,
    unsigned long long c_batch, int Kdim, const float* __restrict__ scale_p,
    float* __restrict__ pss, unsigned int* __restrict__ flags) {
  constexpr int BNR = NF * 64;
  constexpr int JQ = NF / 2;
  const int lane = t & 63;
  const int w = t >> 6;
  const int wm = (w >> 2) * 128;
  const int wn = (w & 3) * (NF * 16);
  int tm, tn, tz, grp;
  if constexpr (OUT16) {
    const int L = (blk & 7) * 32 + (blk >> 3);  // XCD-contiguous tiles
    tm = L & 7;
    tn = (L >> 3) & 7;
    tz = L >> 6;
    grp = 0;
  } else {
    const int xcd = blk & 7, s2 = blk >> 3;  // XCD-local row-groups
    grp = xcd * 4 + (s2 >> 3);
    tn = s2 & 7;
    tz = grp >> 3;
    tm = grp & 7;
  }
  const char* Ab = A + (unsigned long long)tz * a_batch +
                   (unsigned long long)(tm * 256) * (unsigned long long)a_pitch;
  const char* Bb = Bt + (unsigned long long)tz * b_batch +
                   (unsigned long long)(tn * BNR) * (unsigned long long)b_pitch;
  const int srow = t >> 2;
  const int scol = ((t & 3) ^ ((t >> 3) & 3)) << 4;
  const int lds_o = t * 16;
  const int mrow = lane & 15, kc = lane >> 4;
  const int koff = (kc ^ ((mrow >> 1) & 3)) << 3;
  const int NT = Kdim >> 6;

  half8 ar0[4][2], ar1[4][2], br0[JQ][2], br1[JQ][2];
  floatx4 acc[8][NF];
#pragma unroll
  for (int i = 0; i < 8; ++i)
#pragma unroll
    for (int j = 0; j < NF; ++j) acc[i][j] = (floatx4){0.f, 0.f, 0.f, 0.f};

  // prologue: tile0 -> buf0 fully; tile1 -> buf1 except its A-half1
  SG_A(0, 0, 0);
  SG_A(0, 0, 1);
  SG_B(0, 0, 0);
  if constexpr (NF == 4) SG_B(0, 0, 1);
  SG_B(1, 1, 0);
  if constexpr (NF == 4) SG_B(1, 1, 1);
  SG_A(1, 1, 0);
  if constexpr (NF == 4)
    asm volatile("s_waitcnt vmcnt(6)" ::: "memory");
  else
    asm volatile("s_waitcnt vmcnt(4)" ::: "memory");
  G_BAR;
  LDA_(0, 0, ar0);
  LDB_(0, 0, br0);

#define TILE_(bf, nb, u)                                   \
  do {                                                     \
    const int k1_ = ((u) + 1 < NT) ? (u) + 1 : NT - 1;     \
    const int k2_ = ((u) + 2 < NT) ? (u) + 2 : NT - 1;     \
    /* P0 */                                               \
    SG_A(nb, k1_, 1);                                      \
    G_BAR;                                                 \
    LDB_(bf, 1, br1);                                      \
    QUAD(0, 0, ar0, br0);                                  \
    /* P1 */                                               \
    G_BAR;                                                 \
    LDA_(bf, 1, ar1);                                      \
    QUAD(0, 1, ar0, br1);                                  \
    /* P2 */                                               \
    SG_B(bf, k2_, 0);                                      \
    G_BAR;                                                 \
    QUAD(1, 0, ar1, br0);                                  \
    /* P3 */                                               \
    if constexpr (NF == 4) SG_B(bf, k2_, 1);               \
    SG_A(bf, k2_, 0);                                      \
    if constexpr (NF == 4)                                 \
      asm volatile("s_waitcnt vmcnt(6)" ::: "memory");     \
    else                                                   \
      asm volatile("s_waitcnt vmcnt(4)" ::: "memory");     \
    G_BAR;                                                 \
    LDA_(nb, 0, ar0); /* next tile's quad-(0,0), buf nb */ \
    LDB_(nb, 0, br0);                                      \
    QUAD(1, 1, ar1, br1);                                  \
  } while (0)

  for (int u = 0; u < NT; u += 2) {  // NT even (16 or 32)
    TILE_(0, 1, u);
    TILE_(1, 0, u + 1);
  }
  asm volatile("s_waitcnt vmcnt(0)" ::: "memory");  // drain tail restages
#undef TILE_

  const int m0 = tm * 256 + wm;
  const int n0 = tn * BNR + wn;
  const int ccol = lane & 15;
  const int rq = (lane >> 4) * 4;  // C/D: col=lane&15, row=(lane>>4)*4+reg
  if constexpr (OUT16) {
    const float aexp = 2.0f / scale_p[0];
    h16* Cb = (h16*)C + (unsigned long long)tz * c_batch;
#pragma unroll
    for (int i = 0; i < 8; ++i)
#pragma unroll
      for (int j = 0; j < NF; ++j)
#pragma unroll
        for (int r = 0; r < 4; ++r)
          Cb[(unsigned long long)(m0 + i * 16 + rq + r) * c_pitch +
             (n0 + j * 16 + ccol)] = (h16)__expf(acc[i][j][r] * aexp - 8.0f);
  } else {
    float* Cb = (float*)C + (unsigned long long)tz * c_batch;
    // ---- fused row-normalize (R7 form, HW-validated) ----
    __syncthreads();  // all gl_lds writes drained; LDS reusable as scratch
    float* wsum = (float*)as_base;  // [4][256] per-n-wave partials
    float* finv = wsum + 4 * 256;   // [256] rsqrt(ss) per local row
    float part[8][4];
#pragma unroll
    for (int i = 0; i < 8; ++i)
#pragma unroll
      for (int r = 0; r < 4; ++r) {
        float s = acc[i][0][r] * acc[i][0][r];
        if constexpr (NF > 1) s += acc[i][1][r] * acc[i][1][r];
#pragma unroll
        for (int m = 1; m < 16; m <<= 1) s += __shfl_xor(s, m);
        part[i][r] = s;
      }
    if ((lane & 15) == 0) {
#pragma unroll
      for (int i = 0; i < 8; ++i)
#pragma unroll
        for (int r = 0; r < 4; ++r)
          wsum[(w & 3) * 256 + wm + i * 16 + rq + r] = part[i][r];
    }
    __syncthreads();
    if (t < 256) {
      float s = wsum[t] + wsum[256 + t] + wsum[512 + t] + wsum[768 + t];
      __hip_atomic_fetch_add(&pss[(unsigned)grp * 256 + t], s,
                             __ATOMIC_RELAXED, __HIP_MEMORY_SCOPE_AGENT);
    }
    __syncthreads();  // all pss adds issued before the release-add
    if (t == 0) {
      __hip_atomic_fetch_add(&flags[grp], 1u, __ATOMIC_ACQ_REL,
                             __HIP_MEMORY_SCOPE_AGENT);
      while (__hip_atomic_load(&flags[grp], __ATOMIC_ACQUIRE,
                               __HIP_MEMORY_SCOPE_AGENT) < 8u)
        __builtin_amdgcn_s_sleep(2);
    }
    __syncthreads();
    if (t < 256) {
      float ss2 = __hip_atomic_load(&pss[(unsigned)grp * 256 + t],
                                    __ATOMIC_RELAXED, __HIP_MEMORY_SCOPE_AGENT);
      finv[t] = rsqrtf(fmaxf(ss2, 1e-30f));
    }
    __syncthreads();
#pragma unroll
    for (int i = 0; i < 8; ++i) {
#pragma unroll
      for (int r = 0; r < 4; ++r) {
        const float f = finv[wm + i * 16 + rq + r];  // LDS broadcast
#pragma unroll
        for (int j = 0; j < NF; ++j)
          Cb[(unsigned long long)(m0 + i * 16 + rq + r) * c_pitch +
             (n0 + j * 16 + ccol)] = acc[i][j][r] * f;
      }
    }
  }
}

__global__ __launch_bounds__(512, 2) void k_mega(
    const float* __restrict__ Q, const float* __restrict__ rot,
    h16* __restrict__ Qh, h16* __restrict__ Kh, h16* __restrict__ VhT,
    h16* __restrict__ Sl, float* __restrict__ O,
    const float* __restrict__ scale_p, float* __restrict__ pss,
    unsigned int* __restrict__ flags, unsigned int* __restrict__ bar) {
  __shared__ __align__(16) h16 AsS[2][2][256 * 32];  // 64 KiB
  __shared__ __align__(16) h16 BsS[2][2][256 * 32];  // 64 KiB
  h16* as_base = &AsS[0][0][0];
  h16* bs_base = &BsS[0][0][0];
  const int blk = blockIdx.x;  // 0..255, 1 block/CU (128KiB LDS)
  const int t = threadIdx.x;

  // ---- stage 0: prep (8 tiles of 64s x 64d per block) + scratch zeroing ----
  if (t < 32) pss[blk * 32 + t] = 0.f;  // 256*32 = 8192 floats
  if (blk == 0 && t < 32) flags[t] = 0u;
  h16* tile = as_base;  // 64x64 h16 = 8 KiB
  for (int it = 0; it < 8; ++it) {
    const int gid = blk * 8 + it;  // 0..2047
    const int d0 = (gid & 15) * 64, s0 = ((gid >> 4) & 31) * 64, b = gid >> 9;
    const float* Qb = Q + ((size_t)b * S_ + s0) * D_ + d0;
    h16* Qhb = Qh + ((size_t)b * S_ + s0) * D_ + d0;
    h16* Khb = Kh + ((size_t)b * S_ + s0) * D_ + d0;
    {
      const int row = t >> 3;       // s-local 0..63
      const int col = (t & 7) * 8;  // d-local, multiple of 8
      float4 qa = *(const float4*)&Qb[(size_t)row * D_ + col];
      float4 qb = *(const float4*)&Qb[(size_t)row * D_ + col + 4];
      const int dg = (d0 + col) >> 2;
      float4 r0a = ((const float4*)rot)[dg];
      float4 r0b = ((const float4*)rot)[dg + 1];
      float4 r1a = ((const float4*)rot)[D_ / 4 + dg];
      float4 r1b = ((const float4*)rot)[D_ / 4 + dg + 1];
      float4 r2a = ((const float4*)rot)[2 * D_ / 4 + dg];
      float4 r2b = ((const float4*)rot)[2 * D_ / 4 + dg + 1];
      float y0, y1, y2, y3, y4, y5, y6, y7;
      float v0, v1, v2, v3, v4, v5, v6, v7;
      rot_pair(qa.x, qa.y, r0a.x, r0a.y, r1a.x, r1a.y, r2a.x, r2a.y, y0, y1,
               v0, v1);
      rot_pair(qa.z, qa.w, r0a.z, r0a.w, r1a.z, r1a.w, r2a.z, r2a.w, y2, y3,
               v2, v3);
      rot_pair(qb.x, qb.y, r0b.x, r0b.y, r1b.x, r1b.y, r2b.x, r2b.y, y4, y5,
               v4, v5);
      rot_pair(qb.z, qb.w, r0b.z, r0b.w, r1b.z, r1b.w, r2b.z, r2b.w, y6, y7,
               v6, v7);
      half8 qh = {(h16)qa.x, (h16)qa.y, (h16)qa.z, (h16)qa.w,
                  (h16)qb.x, (h16)qb.y, (h16)qb.z, (h16)qb.w};
      half8 kh = {(h16)y0, (h16)y1, (h16)y2, (h16)y3,
                  (h16)y4, (h16)y5, (h16)y6, (h16)y7};
      half8 vh = {(h16)v0, (h16)v1, (h16)v2, (h16)v3,
                  (h16)v4, (h16)v5, (h16)v6, (h16)v7};
      *(half8*)&Qhb[(size_t)row * D_ + col] = qh;
      *(half8*)&Khb[(size_t)row * D_ + col] = kh;
      const int pcol = col ^ ((row >> 3) << 3);  // XOR swizzle, 16B-aligned
      *(half8*)&tile[row * 64 + pcol] = vh;
    }
    __syncthreads();
    {
      h16* dst = VhT + ((size_t)b * D_ + d0) * S_ + s0;
      const int drow = t >> 3;      // d-local 0..63
      const int sc = (t & 7) * 8;   // s-local, multiple of 8
      const int xr = sc;            // (sc+j)>>3<<3 == sc for j<8
      half8 v;
#pragma unroll
      for (int j = 0; j < 8; ++j) v[j] = tile[(sc + j) * 64 + (drow ^ xr)];
      *(half8*)&dst[(size_t)drow * S_ + sc] = v;
    }
    __syncthreads();
  }

  // ---- barrier; then GEMM1: P = exp(alpha*(Qh.Kh^T) - 8), fp16 ----
  dev_barrier(bar, t);
  gemm_body<4, true>(blk, t, as_base, bs_base, (const char*)Qh, D_ * 2,
                     (unsigned long long)S_ * D_ * 2, (const char*)Kh, D_ * 2,
                     (unsigned long long)S_ * D_ * 2, (void*)Sl, S_,
                     (unsigned long long)S_ * S_, D_, scale_p, nullptr,
                     nullptr);

  // ---- barrier; then GEMM2: U = P.VhT^T, fused row-normalize, fp32 ----
  dev_barrier(bar, t);
  gemm_body<2, false>(blk, t, as_base, bs_base, (const char*)Sl, S_ * 2,
                      (unsigned long long)S_ * S_ * 2, (const char*)VhT,
                      S_ * 2, (unsigned long long)D_ * S_ * 2, (void*)O, D_,
                      (unsigned long long)S_ * D_, S_, nullptr, pss, flags);
}

extern "C" void kernel_launch(void* const* d_in, const int* in_sizes, int n_in,
                              void* d_out, int out_size, void* d_ws,
                              size_t ws_size, hipStream_t stream) {
  const float* Q = (const float*)d_in[0];
  const float* rot = (const float*)d_in[1];
  const float* scale = (const float*)d_in[2];
  // bias (d_in[3]) is a scalar added to all logits -> cancels in softmax.
  float* O = (float*)d_out;
  char* ws = (char*)d_ws;
  const size_t MB = 1024ull * 1024ull;
  h16* Qh = (h16*)(ws);             // 16 MB  [B][S][D]
  h16* Kh = (h16*)(ws + 16 * MB);   // 16 MB  [B][S][D]  combined-rotated
  h16* VhT = (h16*)(ws + 32 * MB);  // 16 MB  [B][D][S]  Rv-rotated, transposed
  h16* Sl = (h16*)(ws + 48 * MB);   // 32 MB  [B][S][S] fp16 P (exp fused)
  float* pss = (float*)(ws + 80 * MB);                         // 32 KB
  unsigned int* flags = (unsigned int*)(ws + 80 * MB + 32 * 1024);  // 128 B
  unsigned int* bar = (unsigned int*)(ws + 80 * MB + 33 * 1024);    // 64 B
  // zero the ticket-barrier counter (in-graph, stream-ordered, replay-safe)
  hipMemsetAsync(bar, 0, 64, stream);
  k_mega<<<dim3(256), 512, 0, stream>>>(Q, rot, Qh, Kh, VhT, Sl, O, scale, pss,
                                        flags, bar);
}

// Round 10
// 177.464 us; speedup vs baseline: 1.5126x; 1.5126x over previous
//
#include <hip/hip_runtime.h>

typedef _Float16 h16;
typedef _Float16 half8 __attribute__((ext_vector_type(8)));
typedef float floatx4 __attribute__((ext_vector_type(4)));

static constexpr int Bb_ = 4, S_ = 2048, D_ = 1024;

static __device__ __forceinline__ void gl_lds16(const void* g, void* l) {
  __builtin_amdgcn_global_load_lds(
      (const __attribute__((address_space(1))) unsigned int*)g,
      (__attribute__((address_space(3))) unsigned int*)l, 16, 0, 0);
}

// one 2x2 Givens pair: y = (Rq^T Rk) q (combined, normalized), v = Rv q
static __device__ __forceinline__ void rot_pair(float q0, float q1, float a0,
                                                float a1, float b0, float b1,
                                                float c0, float c1, float& y0,
                                                float& y1, float& v0,
                                                float& v1) {
  float iqk = rsqrtf((a0 * a0 + a1 * a1) * (b0 * b0 + b1 * b1));
  float cc = (a0 * b0 + a1 * b1) * iqk;
  float ss = (a0 * b1 - a1 * b0) * iqk;
  y0 = cc * q0 - ss * q1;
  y1 = cc * q1 + ss * q0;
  float iv = rsqrtf(c0 * c0 + c1 * c1);
  float cv = c0 * iv, sv = c1 * iv;
  v0 = cv * q0 - sv * q1;
  v1 = cv * q1 + sv * q0;
}

// ---- fused prep: Qh = fp16(Q), Kh = fp16(Rq^T Rk Q), VhT = (Rv Q)^T fp16 ----
// Rv folded here (ave.Rv = P.(Rv Q) by linearity). LDS transpose tile uses XOR
// swizzle (phys elem = e ^ 8*(row>>3)); half8 16B stores. Also zero-inits
// GEMM2's pss (32 KB) + flags (kernel-boundary coherence).
__global__ __launch_bounds__(256) void k_prep_t(
    const float* __restrict__ Q, const float* __restrict__ rot,
    h16* __restrict__ Qh, h16* __restrict__ Kh, h16* __restrict__ VhT,
    float* __restrict__ pss, unsigned int* __restrict__ flags) {
  __shared__ __align__(16) h16 tile[64][64];
  int d0 = blockIdx.x * 64, s0 = blockIdx.y * 64, b = blockIdx.z;
  int t = threadIdx.x;
  int bl = blockIdx.x + 16 * (blockIdx.y + 32 * blockIdx.z);  // 0..2047
  if (flags && bl == 0 && t < 32) flags[t] = 0u;
  if (pss && t < 4) pss[bl * 4 + t] = 0.f;  // 2048*4 = 8192 = 32*256 floats
  const float* Qb = Q + ((size_t)b * S_ + s0) * D_ + d0;
  h16* Qhb = Qh + ((size_t)b * S_ + s0) * D_ + d0;
  h16* Khb = Kh + ((size_t)b * S_ + s0) * D_ + d0;
#pragma unroll
  for (int i = 0; i < 2; ++i) {
    int c = t + 256 * i;    // 0..511 8-col chunks of the 64x64 tile
    int row = c >> 3;       // s-local
    int col = (c & 7) * 8;  // d-local, multiple of 8
    float4 qa = *(const float4*)&Qb[(size_t)row * D_ + col];
    float4 qb = *(const float4*)&Qb[(size_t)row * D_ + col + 4];
    int dg = (d0 + col) >> 2;
    float4 r0a = ((const float4*)rot)[dg];
    float4 r0b = ((const float4*)rot)[dg + 1];
    float4 r1a = ((const float4*)rot)[D_ / 4 + dg];
    float4 r1b = ((const float4*)rot)[D_ / 4 + dg + 1];
    float4 r2a = ((const float4*)rot)[2 * D_ / 4 + dg];
    float4 r2b = ((const float4*)rot)[2 * D_ / 4 + dg + 1];
    float y0, y1, y2, y3, y4, y5, y6, y7;
    float v0, v1, v2, v3, v4, v5, v6, v7;
    rot_pair(qa.x, qa.y, r0a.x, r0a.y, r1a.x, r1a.y, r2a.x, r2a.y, y0, y1, v0, v1);
    rot_pair(qa.z, qa.w, r0a.z, r0a.w, r1a.z, r1a.w, r2a.z, r2a.w, y2, y3, v2, v3);
    rot_pair(qb.x, qb.y, r0b.x, r0b.y, r1b.x, r1b.y, r2b.x, r2b.y, y4, y5, v4, v5);
    rot_pair(qb.z, qb.w, r0b.z, r0b.w, r1b.z, r1b.w, r2b.z, r2b.w, y6, y7, v6, v7);
    half8 qh = {(h16)qa.x, (h16)qa.y, (h16)qa.z, (h16)qa.w,
                (h16)qb.x, (h16)qb.y, (h16)qb.z, (h16)qb.w};
    half8 kh = {(h16)y0, (h16)y1, (h16)y2, (h16)y3,
                (h16)y4, (h16)y5, (h16)y6, (h16)y7};
    half8 vh = {(h16)v0, (h16)v1, (h16)v2, (h16)v3,
                (h16)v4, (h16)v5, (h16)v6, (h16)v7};
    *(half8*)&Qhb[(size_t)row * D_ + col] = qh;
    *(half8*)&Khb[(size_t)row * D_ + col] = kh;
    int pcol = col ^ ((row >> 3) << 3);  // XOR swizzle, 16B-aligned
    *(half8*)&tile[row][pcol] = vh;
  }
  __syncthreads();
  h16* dst = VhT + ((size_t)b * D_ + d0) * S_ + s0;
#pragma unroll
  for (int i = 0; i < 2; ++i) {
    int c = t + 256 * i;   // 0..511 half8 chunks of the transposed tile
    int drow = c >> 3;     // d-local
    int sc = (c & 7) * 8;  // s-local, multiple of 8
    int xr = sc;           // (sc+j)>>3<<3 == sc for j<8
    half8 v;
#pragma unroll
    for (int j = 0; j < 8; ++j) v[j] = tile[sc + j][drow ^ xr];
    *(half8*)&dst[(size_t)drow * S_ + sc] = v;
  }
}

// ---------------- 256-wide pipelined GEMM  C[m][n] = sum_k A[m][k]*Bt[n][k]
// K-loop: R4 form (best measured: 43.9/43.9 us across 6 variants tested).
// R10 change: GEMM2 remap REVERTED to the R4/R5 XCD-contiguous form.
// R6/R7's XCD-local map streamed all 8 B-panels (4 MB = one full L2) + the
// A-panel through a single XCD's L2 -> thrash (FETCH dropped 41->33 MB but
// time rose 54.3->56.3; L3 absorbed the extra L2 misses). R4's map, under
// which the GEMM phase measured 43.9, spreads a row-group over 2 XCDs.
// atomicAdd normalize kept (strictly less sync traffic than publish/gather).
// Group (tz,tm) = 8 tn-blocks on 2 XCDs; all 256 wgs co-resident (1 block/CU)
// -> spin `< 8` terminates; monotone so stale-flag rocprof replays exit.
// OUT16 (GEMM1): P = exp(l*alpha - 8) fused in C-store (constant shift
// cancels under the final normalize; alpha*l ~ N(0,4) cannot overflow fp16).
//   NF=4 (GEMM1): 256x256 tile, grid 8x8x4 = 256 wgs, 128 KiB LDS.
//   NF=2 (GEMM2): 256x128 tile, grid 8x8x4 = 256 wgs,  96 KiB LDS.
#define G_FENCE asm volatile("" ::: "memory")
#define G_BAR                     \
  do {                            \
    G_FENCE;                      \
    __builtin_amdgcn_s_barrier(); \
    G_FENCE;                      \
  } while (0)

template <int NF, bool OUT16>
__global__ __launch_bounds__(512, 2) void k_gemm8(
    const char* __restrict__ A, int a_pitch, unsigned long long a_batch,
    const char* __restrict__ Bt, int b_pitch, unsigned long long b_batch,
    void* __restrict__ C, int c_pitch, unsigned long long c_batch, int Kdim,
    const float* __restrict__ scale_p, float* __restrict__ pss,
    unsigned int* __restrict__ flags) {
  constexpr int BNR = NF * 64;  // B-tile rows (N-tile size): 256 or 128
  constexpr int JQ = NF / 2;    // B frags per quadrant: 2 or 1
  __shared__ __align__(16) h16 As[2][2][256 * 32];
  __shared__ __align__(16) h16 Bs[2][2][BNR * 32];
  const int t = threadIdx.x;
  const int lane = t & 63;
  const int w = t >> 6;
  const int wm = (w >> 2) * 128;
  const int wn = (w & 3) * (NF * 16);
  // XCD-contiguous remap (R4 form) for BOTH gemms: each XCD gets 32
  // consecutive linear tiles; a GEMM2 row-group (tz,tm) spans 2 XCDs.
  const int id = blockIdx.x + 8 * (blockIdx.y + 8 * blockIdx.z);
  const int L = (id & 7) * 32 + (id >> 3);
  const int tm = L & 7, tn = (L >> 3) & 7, tz = L >> 6;
  const int grp = tz * 8 + tm;  // GEMM2 row-group id, 0..31
  const char* Ab = A + (unsigned long long)tz * a_batch +
                   (unsigned long long)(tm * 256) * (unsigned long long)a_pitch;
  const char* Bb = Bt + (unsigned long long)tz * b_batch +
                   (unsigned long long)(tn * BNR) * (unsigned long long)b_pitch;
  // staging: thread t covers 16B; 512 thr = one 128-row x 32-half slab (8 KB)
  const int srow = t >> 2;                           // slab-local row 0..127
  const int scol = ((t & 3) ^ ((t >> 3) & 3)) << 4;  // pre-swizzled src chunk
  const int lds_o = t * 16;                          // linear LDS dest
  const int mrow = lane & 15, kc = lane >> 4;
  const int koff = (kc ^ ((mrow >> 1) & 3)) << 3;  // swizzled read offset
  const int NT = Kdim >> 6;

#define SG_A(bf, kt, hm)                                                  \
  do {                                                                    \
    const char* sp_ = Ab +                                                \
                      (unsigned long long)(srow + (hm) * 128) * a_pitch + \
                      (kt) * 128 + scol;                                  \
    gl_lds16(sp_, (char*)&As[bf][0][(hm) * 128 * 32] + lds_o);            \
    gl_lds16(sp_ + 64, (char*)&As[bf][1][(hm) * 128 * 32] + lds_o);       \
  } while (0)
#define SG_B(bf, kt, hm)                                                  \
  do {                                                                    \
    const char* sp_ = Bb +                                                \
                      (unsigned long long)(srow + (hm) * 128) * b_pitch + \
                      (kt) * 128 + scol;                                  \
    gl_lds16(sp_, (char*)&Bs[bf][0][(hm) * 128 * 32] + lds_o);            \
    gl_lds16(sp_ + 64, (char*)&Bs[bf][1][(hm) * 128 * 32] + lds_o);       \
  } while (0)

  half8 ar0[4][2], ar1[4][2], br0[JQ][2], br1[JQ][2];
  floatx4 acc[8][NF];
#pragma unroll
  for (int i = 0; i < 8; ++i)
#pragma unroll
    for (int j = 0; j < NF; ++j) acc[i][j] = (floatx4){0.f, 0.f, 0.f, 0.f};

#define LDA_(bf, mh, DST)                                                \
  do {                                                                   \
    _Pragma("unroll") for (int i_ = 0; i_ < 4; ++i_) {                   \
      DST[i_][0] = *(const half8*)&As[bf][0]                             \
                       [(wm + ((mh) * 4 + i_) * 16 + mrow) * 32 + koff]; \
      DST[i_][1] = *(const half8*)&As[bf][1]                             \
                       [(wm + ((mh) * 4 + i_) * 16 + mrow) * 32 + koff]; \
    }                                                                    \
  } while (0)
#define LDB_(bf, nh, DST)                                                \
  do {                                                                   \
    _Pragma("unroll") for (int j_ = 0; j_ < JQ; ++j_) {                  \
      DST[j_][0] = *(const half8*)&Bs[bf][0]                             \
                       [(wn + ((nh)*JQ + j_) * 16 + mrow) * 32 + koff];  \
      DST[j_][1] = *(const half8*)&Bs[bf][1]                             \
                       [(wn + ((nh)*JQ + j_) * 16 + mrow) * 32 + koff];  \
    }                                                                    \
  } while (0)
#define QUAD(mh, nh, AF, BF)                                                 \
  do {                                                                       \
    __builtin_amdgcn_s_setprio(1);                                           \
    _Pragma("unroll") for (int i_ = 0; i_ < 4; ++i_)                         \
        _Pragma("unroll") for (int j_ = 0; j_ < JQ; ++j_) {                  \
      acc[(mh) * 4 + i_][(nh)*JQ + j_] =                                     \
          __builtin_amdgcn_mfma_f32_16x16x32_f16(                            \
              AF[i_][0], BF[j_][0], acc[(mh) * 4 + i_][(nh)*JQ + j_], 0, 0,  \
              0);                                                            \
      acc[(mh) * 4 + i_][(nh)*JQ + j_] =                                     \
          __builtin_amdgcn_mfma_f32_16x16x32_f16(                            \
              AF[i_][1], BF[j_][1], acc[(mh) * 4 + i_][(nh)*JQ + j_], 0, 0,  \
              0);                                                            \
    }                                                                        \
    __builtin_amdgcn_s_setprio(0);                                           \
  } while (0)

  // prologue: tile0 -> buf0 fully; tile1 -> buf1 except its A-half1
  SG_A(0, 0, 0);
  SG_A(0, 0, 1);
  SG_B(0, 0, 0);
  if constexpr (NF == 4) SG_B(0, 0, 1);
  SG_B(1, 1, 0);
  if constexpr (NF == 4) SG_B(1, 1, 1);
  SG_A(1, 1, 0);
  if constexpr (NF == 4)
    asm volatile("s_waitcnt vmcnt(6)" ::: "memory");
  else
    asm volatile("s_waitcnt vmcnt(4)" ::: "memory");
  G_BAR;
  LDA_(0, 0, ar0);  // tile0 quad-(0,0) frags: in flight into P0's MFMA
  LDB_(0, 0, br0);

#define TILE_(bf, nb, u)                                   \
  do {                                                     \
    const int k1_ = ((u) + 1 < NT) ? (u) + 1 : NT - 1;     \
    const int k2_ = ((u) + 2 < NT) ? (u) + 2 : NT - 1;     \
    /* P0 */                                               \
    SG_A(nb, k1_, 1);                                      \
    G_BAR;                                                 \
    LDB_(bf, 1, br1);                                      \
    QUAD(0, 0, ar0, br0);                                  \
    /* P1 */                                               \
    G_BAR;                                                 \
    LDA_(bf, 1, ar1);                                      \
    QUAD(0, 1, ar0, br1);                                  \
    /* P2 */                                               \
    SG_B(bf, k2_, 0);                                      \
    G_BAR;                                                 \
    QUAD(1, 0, ar1, br0);                                  \
    /* P3 */                                               \
    if constexpr (NF == 4) SG_B(bf, k2_, 1);               \
    SG_A(bf, k2_, 0);                                      \
    if constexpr (NF == 4)                                 \
      asm volatile("s_waitcnt vmcnt(6)" ::: "memory");     \
    else                                                   \
      asm volatile("s_waitcnt vmcnt(4)" ::: "memory");     \
    G_BAR;                                                 \
    LDA_(nb, 0, ar0); /* next tile's quad-(0,0), buf nb */ \
    LDB_(nb, 0, br0);                                      \
    QUAD(1, 1, ar1, br1);                                  \
  } while (0)

  for (int u = 0; u < NT; u += 2) {  // NT is even (16 or 32)
    TILE_(0, 1, u);
    TILE_(1, 0, u + 1);
  }
  asm volatile("s_waitcnt vmcnt(0)" ::: "memory");  // drain tail restages

  const int m0 = tm * 256 + wm;
  const int n0 = tn * BNR + wn;
  const int ccol = lane & 15;
  const int rq = (lane >> 4) * 4;  // C/D: col=lane&15, row=(lane>>4)*4+reg
  if constexpr (OUT16) {
    // fused softmax numerator: P = exp(l*alpha - 8); constant shift cancels
    // in the final normalize. alpha*l ~ N(0,4): no fp16 overflow.
    const float aexp = 2.0f / scale_p[0];
    h16* Cb = (h16*)C + (unsigned long long)tz * c_batch;
#pragma unroll
    for (int i = 0; i < 8; ++i)
#pragma unroll
      for (int j = 0; j < NF; ++j)
#pragma unroll
        for (int r = 0; r < 4; ++r)
          Cb[(unsigned long long)(m0 + i * 16 + rq + r) * c_pitch +
             (n0 + j * 16 + ccol)] = (h16)__expf(acc[i][j][r] * aexp - 8.0f);
  } else {
    float* Cb = (float*)C + (unsigned long long)tz * c_batch;
    if (pss) {
      // ---- fused row-normalize (atomicAdd form, R6) ----
      __syncthreads();                     // all gl_lds drained; LDS reusable
      float* wsum = (float*)&As[0][0][0];  // [4][256] per-n-wave partials
      float* finv = wsum + 4 * 256;        // [256] rsqrt(ss) per local row
      float part[8][4];
#pragma unroll
      for (int i = 0; i < 8; ++i)
#pragma unroll
        for (int r = 0; r < 4; ++r) {
          float s = acc[i][0][r] * acc[i][0][r];
          if constexpr (NF > 1) s += acc[i][1][r] * acc[i][1][r];
#pragma unroll
          for (int m = 1; m < 16; m <<= 1) s += __shfl_xor(s, m);
          part[i][r] = s;
        }
      if ((lane & 15) == 0) {
#pragma unroll
        for (int i = 0; i < 8; ++i)
#pragma unroll
          for (int r = 0; r < 4; ++r)
            wsum[(w & 3) * 256 + wm + i * 16 + rq + r] = part[i][r];
      }
      __syncthreads();
      if (t < 256) {
        float s = wsum[t] + wsum[256 + t] + wsum[512 + t] + wsum[768 + t];
        __hip_atomic_fetch_add(&pss[(unsigned)grp * 256 + t], s,
                               __ATOMIC_RELAXED, __HIP_MEMORY_SCOPE_AGENT);
      }
      __syncthreads();  // all pss adds issued before the release-add
      if (t == 0) {
        __hip_atomic_fetch_add(&flags[grp], 1u, __ATOMIC_ACQ_REL,
                               __HIP_MEMORY_SCOPE_AGENT);
        while (__hip_atomic_load(&flags[grp], __ATOMIC_ACQUIRE,
                                 __HIP_MEMORY_SCOPE_AGENT) < 8u)
          __builtin_amdgcn_s_sleep(2);
      }
      __syncthreads();
      if (t < 256) {
        float ss2 = __hip_atomic_load(&pss[(unsigned)grp * 256 + t],
                                      __ATOMIC_RELAXED,
                                      __HIP_MEMORY_SCOPE_AGENT);
        finv[t] = rsqrtf(fmaxf(ss2, 1e-30f));
      }
      __syncthreads();
#pragma unroll
      for (int i = 0; i < 8; ++i) {
#pragma unroll
        for (int r = 0; r < 4; ++r) {
          const float f = finv[wm + i * 16 + rq + r];  // LDS broadcast
#pragma unroll
          for (int j = 0; j < NF; ++j)
            Cb[(unsigned long long)(m0 + i * 16 + rq + r) * c_pitch +
               (n0 + j * 16 + ccol)] = acc[i][j][r] * f;
        }
      }
    } else {
#pragma unroll
      for (int i = 0; i < 8; ++i)
#pragma unroll
        for (int j = 0; j < NF; ++j)
#pragma unroll
          for (int r = 0; r < 4; ++r)
            Cb[(unsigned long long)(m0 + i * 16 + rq + r) * c_pitch +
               (n0 + j * 16 + ccol)] = acc[i][j][r];
    }
  }
#undef TILE_
#undef QUAD
#undef LDB_
#undef LDA_
#undef SG_B
#undef SG_A
}

// ---- fallback epilogue (only if ws too small for pss scratch) ----
__global__ __launch_bounds__(256) void k_epilogue(float* __restrict__ O) {
  int wv = threadIdx.x >> 6, ln = threadIdx.x & 63;
  int row = blockIdx.x * 4 + wv;
  float* base = O + (size_t)row * D_;
  float4 u[4];
#pragma unroll
  for (int r = 0; r < 4; ++r) u[r] = ((const float4*)base)[ln + 64 * r];
  float ss = 0.f;
#pragma unroll
  for (int r = 0; r < 4; ++r)
    ss += u[r].x * u[r].x + u[r].y * u[r].y + u[r].z * u[r].z + u[r].w * u[r].w;
#pragma unroll
  for (int off = 32; off; off >>= 1) ss += __shfl_xor(ss, off);
  float f = rsqrtf(fmaxf(ss, 1e-30f));
#pragma unroll
  for (int r = 0; r < 4; ++r) {
    float4 o;
    o.x = u[r].x * f;
    o.y = u[r].y * f;
    o.z = u[r].z * f;
    o.w = u[r].w * f;
    ((float4*)base)[ln + 64 * r] = o;
  }
}

extern "C" void kernel_launch(void* const* d_in, const int* in_sizes, int n_in,
                              void* d_out, int out_size, void* d_ws, size_t ws_size,
                              hipStream_t stream) {
  const float* Q = (const float*)d_in[0];
  const float* rot = (const float*)d_in[1];
  const float* scale = (const float*)d_in[2];
  // bias (d_in[3]) is a scalar added to all logits -> cancels in softmax exactly.
  float* O = (float*)d_out;
  char* ws = (char*)d_ws;
  const size_t MB = 1024ull * 1024ull;
  h16* Qh = (h16*)(ws);             // 16 MB  [B][S][D]
  h16* Kh = (h16*)(ws + 16 * MB);   // 16 MB  [B][S][D]  combined-rotated
  h16* VhT = (h16*)(ws + 32 * MB);  // 16 MB  [B][D][S]  Rv-rotated, transposed
  h16* Sl = (h16*)(ws + 48 * MB);   // 32 MB  [B][S][S] fp16 P (exp fused)
  // GEMM2 normalize scratch: pss 32 grp x 256 rows f32 (32 KB) + 32 flags
  float* pss = (float*)(ws + 80 * MB);
  unsigned int* flags = (unsigned int*)(ws + 80 * MB + 32 * 1024);
  const bool fused = ws_size >= 80 * MB + 32 * 1024 + 128;
  if (!fused) {
    pss = nullptr;
    flags = nullptr;
  }

  k_prep_t<<<dim3(D_ / 64, S_ / 64, Bb_), 256, 0, stream>>>(Q, rot, Qh, Kh,
                                                            VhT, pss, flags);
  // GEMM1: P[m][n] = exp(alpha * (Qh[m].Kh[n]) - 8)   (M=N=2048, K=1024), fp16
  k_gemm8<4, true><<<dim3(8, 8, 4), 512, 0, stream>>>(
      (const char*)Qh, D_ * 2, (unsigned long long)S_ * D_ * 2,
      (const char*)Kh, D_ * 2, (unsigned long long)S_ * D_ * 2,
      (void*)Sl, S_, (unsigned long long)S_ * S_, D_, scale, nullptr, nullptr);
  // GEMM2: U[m][d] = P[m] . VhT[d]  (M=2048, N=1024, K=2048), fp32 out,
  // row-normalize fused via pss/flags (falls back to k_epilogue if no scratch)
  k_gemm8<2, false><<<dim3(8, 8, 4), 512, 0, stream>>>(
      (const char*)Sl, S_ * 2, (unsigned long long)S_ * S_ * 2,
      (const char*)VhT, S_ * 2, (unsigned long long)D_ * S_ * 2,
      (void*)O, D_, (unsigned long long)S_ * D_, S_, nullptr, pss, flags);
  if (!fused) k_epilogue<<<dim3(Bb_ * S_ / 4), 256, 0, stream>>>(O);
}